// Round 9
// baseline (1139.361 us; speedup 1.0000x reference)
//
#include <hip/hip_runtime.h>
#include <math.h>

#define NCH 32
#define NB  16
#define HW  128
#define NPIX (HW*HW)
#define NPROB 8194

typedef float v2f __attribute__((ext_vector_type(2)));

__device__ __forceinline__ float2 cmulf(float2 a, float2 b) {
    return make_float2(a.x*b.x - a.y*b.y, a.x*b.y + a.y*b.x);
}
__device__ __forceinline__ int rev7(int i) { return (int)(__brev((unsigned)i) >> 25); }
// HW trig: input in revolutions (angle/2pi). Exact for dyadic-rational inputs.
__device__ __forceinline__ float hw_sin(float rev) { return __builtin_amdgcn_sinf(rev); }
__device__ __forceinline__ float hw_cos(float rev) { return __builtin_amdgcn_cosf(rev); }

// ---- packed fp32 helpers (CDNA v_pk_* ; hipcc never auto-generates these) ----
// D = A*B + C (elementwise 2-wide)
__device__ __forceinline__ v2f pk_fma(v2f a, v2f b, v2f c) {
    v2f d;
    asm("v_pk_fma_f32 %0, %1, %2, %3" : "=v"(d) : "v"(a), "v"(b), "v"(c));
    return d;
}
// D = A * B.yx + C   (swap halves of B via op_sel)
__device__ __forceinline__ v2f pk_fma_swap1(v2f a, v2f b, v2f c) {
    v2f d;
    asm("v_pk_fma_f32 %0, %1, %2, %3 op_sel:[0,1,0] op_sel_hi:[1,0,1]"
        : "=v"(d) : "v"(a), "v"(b), "v"(c));
    return d;
}
// D = A * B.yx
__device__ __forceinline__ v2f pk_mul_swap1(v2f a, v2f b) {
    v2f d;
    asm("v_pk_mul_f32 %0, %1, %2 op_sel:[0,1] op_sel_hi:[1,0]"
        : "=v"(d) : "v"(a), "v"(b));
    return d;
}

// 128-point radix-2 DIF FFT in LDS; 64 lanes cooperate on one transform.
__device__ void fft128(float2* d, int lane, float sign) {
    for (int span = 64; span >= 1; span >>= 1) {
        int k = lane & (span - 1);
        int base = ((lane & ~(span - 1)) << 1) | k;
        float2 a = d[base];
        float2 b = d[base + span];
        float2 su = make_float2(a.x + b.x, a.y + b.y);
        float2 df = make_float2(a.x - b.x, a.y - b.y);
        float rev = (float)k / (float)(2 * span);
        float cw = hw_cos(rev);
        float sw = sign * hw_sin(rev);
        d[base] = su;
        d[base + span] = cmulf(df, make_float2(cw, sw));
        __syncthreads();
    }
    float2 v0 = d[rev7(lane)];
    float2 v1 = d[rev7(lane + 64)];
    __syncthreads();
    d[lane] = v0;
    d[lane + 64] = v1;
    __syncthreads();
}

__global__ __launch_bounds__(256) void k_fwd_rows(const float* __restrict__ x,
                                                  float2* __restrict__ XF) {
    __shared__ float2 buf[4][HW];
    int wave = threadIdx.x >> 6, lane = threadIdx.x & 63;
    long row = (long)blockIdx.x * 4 + wave;
    long base = row * HW;
    const float sc = 1.0f / 128.0f;
    float2* d = buf[wave];
    d[lane]      = make_float2(x[base + lane] * sc, 0.f);
    d[lane + 64] = make_float2(x[base + lane + 64] * sc, 0.f);
    __syncthreads();
    fft128(d, lane, -1.f);
    XF[base + lane]      = d[lane];
    XF[base + lane + 64] = d[lane + 64];
}

__global__ __launch_bounds__(256) void k_cols(float2* __restrict__ XF, float sign) {
    __shared__ float2 tile[HW][17];
    int img = blockIdx.x >> 3;
    int w0  = (blockIdx.x & 7) << 4;
    long base = (long)img * NPIX + w0;
    int tid = threadIdx.x;
    for (int it = 0; it < 8; ++it) {
        int flat = it * 256 + tid;
        int h = flat >> 4, c = flat & 15;
        tile[h][c] = XF[base + (long)h * HW + c];
    }
    __syncthreads();
    for (int span = 64; span >= 1; span >>= 1) {
        for (int it = 0; it < 4; ++it) {
            int idx = it * 256 + tid;
            int j = idx >> 4, c = idx & 15;
            int k = j & (span - 1);
            int bidx = ((j & ~(span - 1)) << 1) | k;
            float2 a = tile[bidx][c], b = tile[bidx + span][c];
            float2 su = make_float2(a.x + b.x, a.y + b.y);
            float2 df = make_float2(a.x - b.x, a.y - b.y);
            float rev = (float)k / (float)(2 * span);
            float cw = hw_cos(rev);
            float sw = sign * hw_sin(rev);
            tile[bidx][c] = su;
            tile[bidx + span][c] = cmulf(df, make_float2(cw, sw));
        }
        __syncthreads();
    }
    float2 v[8];
    for (int it = 0; it < 8; ++it) {
        int flat = it * 256 + tid;
        int h = flat >> 4, c = flat & 15;
        v[it] = tile[rev7(h)][c];
    }
    __syncthreads();
    for (int it = 0; it < 8; ++it) {
        int flat = it * 256 + tid;
        int h = flat >> 4, c = flat & 15;
        tile[h][c] = v[it];
    }
    __syncthreads();
    for (int it = 0; it < 8; ++it) {
        int flat = it * 256 + tid;
        int h = flat >> 4, c = flat & 15;
        XF[base + (long)h * HW + c] = tile[h][c];
    }
}

__device__ __forceinline__ void prob_to_hw(int gp, int& h, int& w) {
    if (gp < 8064)      { h = 1 + (gp >> 7); w = gp & 127; }
    else if (gp < 8129) { h = 0;  w = gp - 8064; }
    else                { h = 64; w = gp - 8129; }
}

// pixel (h,w) -> (representative problem gp, conjugate flag)
__device__ __forceinline__ void pix_to_prob(int h, int w, int& gp, bool& cj) {
    if (h >= 1 && h <= 63)      { gp = (h - 1) * 128 + w; cj = false; }
    else if (h >= 65)           { gp = (127 - h) * 128 + ((128 - w) & 127); cj = true; }
    else if (h == 0)            { if (w <= 64) { gp = 8064 + w; cj = false; }
                                  else        { gp = 8064 + 128 - w; cj = true; } }
    else                        { if (w <= 64) { gp = 8129 + w; cj = false; }
                                  else        { gp = 8129 + 128 - w; cj = true; } }
}

// build rows [rh*16, rh*16+16) of K column `col`: b[j] = K_{rh*16+j, col}(h,w)
__device__ __forceinline__ void build_kcol_half(const float* __restrict__ ker,
                                                int h, int w, int col, int rh, v2f* b) {
    float twr[9], twi[9];
    #pragma unroll
    for (int u = 0; u < 3; ++u)
        #pragma unroll
        for (int v = 0; v < 3; ++v) {
            int idx = (h * u + w * v) & 127;
            float rev = (float)idx * (1.0f / 128.0f);
            twr[u * 3 + v] =  hw_cos(rev);
            twi[u * 3 + v] = -hw_sin(rev);
        }
    #pragma unroll
    for (int j = 0; j < 16; ++j) {
        int o = (rh << 4) + j;
        const float* kp = ker + (size_t)(o * NCH + col) * 9;
        float ar = 0.f, ai = 0.f;
        #pragma unroll
        for (int t = 0; t < 9; ++t) { float kv = kp[t]; ar = fmaf(kv, twr[t], ar); ai = fmaf(kv, twi[t], ai); }
        b[j].x = ar; b[j].y = ai;
    }
}

__device__ __forceinline__ float halfsum(float v) {
    v += __shfl_xor(v, 1);  v += __shfl_xor(v, 2);  v += __shfl_xor(v, 4);
    v += __shfl_xor(v, 8);  v += __shfl_xor(v, 16);
    return v;
}
__device__ __forceinline__ float wsum64(float v) {
    v = halfsum(v); v += __shfl_xor(v, 32);
    return v;
}

// One-sided Jacobi SVD per pixel. ONE problem per 64-thread block (1 wave).
// lane (rh,col) owns rows [rh*16,rh*16+16) of column col. Partner column
// fetched once per round into registers; norms tracked analytically; hot
// Gram + rotation loops use packed v_pk_fma_f32 (2 floats/instr).
__global__ __launch_bounds__(64, 1) void k_eig4(
    const float* __restrict__ ker, const float* __restrict__ bias,
    float2* __restrict__ Uws, float* __restrict__ distP, float* __restrict__ biasp)
{
    __shared__ float2 U[16][33];      // selected columns, transposed access

    int l64  = threadIdx.x & 63;
    int rh   = l64 >> 5;
    int col  = l64 & 31;
    int sbase = rh << 5;

    int gp = blockIdx.x;              // grid == NPROB exactly
    int h, w; prob_to_hw(gp, h, w);
    int hc = (128 - h) & 127, wc = (128 - w) & 127;
    bool self = (hc == h && wc == w);

    v2f b[16];
    build_kcol_half(ker, h, w, col, rh, b);

    // tracked column norm^2 (identical across rh halves by construction)
    float cn;
    {
        float nr = 0.f;
        #pragma unroll
        for (int i = 0; i < 16; ++i) nr = fmaf(b[i].x, b[i].x, fmaf(b[i].y, b[i].y, nr));
        cn = nr + __shfl_xor(nr, 32, 64);
    }

    // ---- one-sided Jacobi, XOR-pair ordering over columns ----
    for (int sweep = 0; sweep < 8; ++sweep) {
        float offacc = 0.f;
        for (int m = 1; m < 32; ++m) {
            bool isP = col < (col ^ m);
            // fetch partner half-column ONCE into registers
            v2f F[16];
            #pragma unroll
            for (int i = 0; i < 16; ++i) {
                F[i].x = __shfl_xor(b[i].x, m, 64);
                F[i].y = __shfl_xor(b[i].y, m, 64);
            }
            float nf = __shfl_xor(cn, m, 64);
            // packed partial Gram over own 16 rows:
            // acc1 = (Σ bx*fx, Σ by*fy) ; acc2 = (Σ bx*fy, Σ by*fx)
            v2f acc1 = (v2f)(0.f), acc2 = (v2f)(0.f);
            #pragma unroll
            for (int i = 0; i < 16; ++i) {
                acc1 = pk_fma(b[i], F[i], acc1);
                acc2 = pk_fma_swap1(b[i], F[i], acc2);
            }
            // horizontal + cross-half reduce (order identical across the
            // pair-quad; negation-exact for gim)
            float greP = acc1.x + acc1.y;
            float gimP = isP ? (acc2.x - acc2.y) : (acc2.y - acc2.x);
            float gre = greP + __shfl_xor(greP, 32, 64);
            float gim = gimP + __shfl_xor(gimP, 32, 64);
            float app = isP ? cn : nf;
            float aqq = isP ? nf : cn;
            float n2 = gre * gre + gim * gim;
            offacc += n2;

            bool doRot = (n2 > 1e-24f * app * aqq) && (n2 > 1e-36f);
            if (__ballot(doRot)) {
                float ad  = sqrtf(n2);
                float tau = (aqq - app) / (2.f * ad);
                float tt  = (tau >= 0.f ? 1.f : -1.f) / (fabsf(tau) + sqrtf(fmaf(tau, tau, 1.f)));
                float cc  = rsqrtf(fmaf(tt, tt, 1.f));
                float sg  = tt * cc / ad;
                float ssx = sg * gre, ssy = sg * gim;
                float gx  = isP ? -ssx : ssx;
                float gy  = ssy;
                float dlt = tt * ad;           // diagonal shift
                if (!doRot) { cc = 1.f; gx = 0.f; gy = 0.f; dlt = 0.f; }
                v2f ccv = (v2f)(cc);
                v2f gxv = (v2f)(gx);
                v2f gyv; gyv.x = -gy; gyv.y = gy;
                #pragma unroll
                for (int i = 0; i < 16; ++i) {
                    // t = (-gy*fy, gy*fx) ; t += gx*F ; b = cc*b + t
                    v2f t = pk_mul_swap1(gyv, F[i]);
                    t = pk_fma(gxv, F[i], t);
                    b[i] = pk_fma(ccv, b[i], t);
                }
                cn += isP ? -dlt : dlt;
            }
        }
        // convergence: sum|g|^2 (pair-double-counted) <= 1e-8 * sum(sigma^4)
        float dg   = halfsum(cn * cn);
        float offT = halfsum(offacc);
        if (!__ballot(offT > 1e-8f * dg)) break;
    }

    // ---- top-16 selection by EXACT column norm; write normalized U ----
    float nr = 0.f;
    #pragma unroll
    for (int i = 0; i < 16; ++i) nr = fmaf(b[i].x, b[i].x, fmaf(b[i].y, b[i].y, nr));
    float nrF = nr + __shfl_xor(nr, 32, 64);
    int rank = 0;
    #pragma unroll
    for (int k = 0; k < 32; ++k) {
        float nk = __shfl(nrF, k, 64);
        if (nk > nrF || (nk == nrF && k < col)) ++rank;
    }
    bool sel = rank < 16;
    unsigned long long ball = __ballot(sel);
    unsigned cmask = (unsigned)(ball & 0xFFFFFFFFull);
    int rsel = __popc(cmask & ((1u << col) - 1u));
    float rin = rsqrtf(fmaxf(nrF, 1e-30f));
    if (sel) {
        #pragma unroll
        for (int j = 0; j < 16; ++j) {
            float2 uv = make_float2(b[j].x * rin, b[j].y * rin);
            U[rsel][(rh << 4) + j] = uv;
            Uws[((size_t)gp * 16 + rsel) * 32 + (rh << 4) + j] = uv;
        }
    }
    asm volatile("s_waitcnt lgkmcnt(0)" ::: "memory");
    __builtin_amdgcn_sched_barrier(0);

    // ---- dist: ||K-P||^2 = ||K||^2 - 2 Re tr(K^H P) + 16 ----
    build_kcol_half(ker, h, w, col, rh, b);
    float kn = 0.f;
    #pragma unroll
    for (int j = 0; j < 16; ++j) kn = fmaf(b[j].x, b[j].x, fmaf(b[j].y, b[j].y, kn));
    float knt = wsum64(kn);
    float tr = 0.f;                            // both rh halves count -> 2x
    #pragma unroll
    for (int m = 0; m < 16; ++m) {
        float2 acc = make_float2(0.f, 0.f);
        #pragma unroll
        for (int j = 0; j < 16; ++j) {
            float2 um = U[m][(rh << 4) + j];
            acc.x = fmaf(b[j].x, um.x, fmaf( b[j].y, um.y, acc.x));
            acc.y = fmaf(b[j].x, um.y, fmaf(-b[j].y, um.x, acc.y));
        }
        acc.x += __shfl_xor(acc.x, 32, 64);
        acc.y += __shfl_xor(acc.y, 32, 64);
        float2 w0 = U[m][col];
        tr = fmaf(w0.x, acc.x, fmaf(w0.y, acc.y, tr));
    }
    float trt = wsum64(tr);                    // = 2 * Re tr(K^H P)
    if (l64 == 0) {
        float d2 = knt - trt + 16.f;
        distP[gp] = (self ? 1.f : 2.f) * d2;
    }

    // ---- bias correction at DC pixel (gp==8064 -> (h,w)=(0,0)) ----
    if (gp == 8064) {
        int mmode = col & 15;
        float2 d = make_float2(0.f, 0.f);
        #pragma unroll
        for (int j = 0; j < 16; ++j) {
            int i = (rh << 4) + j;
            float bv = bias[i];
            float2 ul = U[mmode][i];
            d.x = fmaf(ul.x, bv, d.x);
            d.y = fmaf(-ul.y, bv, d.y);
        }
        d.x += __shfl_xor(d.x, 32, 64);
        d.y += __shfl_xor(d.y, 32, 64);
        float racc = 0.f;
        #pragma unroll
        for (int mm = 0; mm < 16; ++mm) {
            float dx = __shfl(d.x, sbase + mm, 64);
            float dy = __shfl(d.y, sbase + mm, 64);
            float2 ul = U[mm][col];
            racc = fmaf(ul.x, dx, fmaf(-ul.y, dy, racc));
        }
        if (rh == 0) biasp[col] = bias[col] - racc;
    }
}

// Apply y_f = conj(P) x_f per pixel, rank-16 form. 8 consecutive pixels per
// block (one 64B line per (b,c) row -> coalesced). U staged in LDS.
// direct: y = conj(U)(U^T x); conj-pixel: y = U (U^H x).
__global__ __launch_bounds__(256) void k_apply(const float2* __restrict__ Uws,
                                               float2* __restrict__ XF)
{
    __shared__ float2 Us[16][33][9];   // [m][i][slot] (pads kill 8-way conflicts)
    __shared__ float2 xs[32][9];       // [c][slot]
    __shared__ float2 ts[16][9];       // [m][slot]

    int tid = threadIdx.x;
    int pb = blockIdx.x * 8;
    int h = pb >> 7, w0 = pb & 127;

    // --- stage U for the 8 pixels of this block ---
    {
        int slot = tid >> 5, t5 = tid & 31;
        int gp; bool cj;
        pix_to_prob(h, w0 + slot, gp, cj);
        size_t gbase = (size_t)gp * 512 + (size_t)t5 * 16;
        #pragma unroll
        for (int j = 0; j < 16; ++j) {
            int e = t5 * 16 + j;
            Us[e >> 5][e & 31][slot] = Uws[gbase + j];
        }
    }
    __syncthreads();

    int c = tid >> 3, ws = tid & 7;
    int gp; bool cj;
    pix_to_prob(h, w0 + ws, gp, cj);
    float sgn = cj ? -1.f : 1.f;
    long pbase = (long)h * 128 + (w0 + ws);

    for (int bb = 0; bb < NB; ++bb) {
        long adr = ((long)(bb * NCH + c)) * NPIX + pbase;
        xs[c][ws] = XF[adr];
        __syncthreads();
        if (c < 16) {
            float2 t = make_float2(0.f, 0.f);
            #pragma unroll
            for (int i = 0; i < 32; ++i) {
                float2 ul = Us[c][i][ws];
                float uy = sgn * ul.y;
                float2 xr = xs[i][ws];
                t.x = fmaf(ul.x, xr.x, fmaf(-uy, xr.y, t.x));
                t.y = fmaf(ul.x, xr.y, fmaf( uy, xr.x, t.y));
            }
            ts[c][ws] = t;
        }
        __syncthreads();
        float2 y = make_float2(0.f, 0.f);
        #pragma unroll
        for (int m = 0; m < 16; ++m) {
            float2 ul = Us[m][c][ws];
            float uy = sgn * ul.y;
            float2 t = ts[m][ws];
            y.x = fmaf(ul.x, t.x, fmaf( uy, t.y, y.x));
            y.y = fmaf(ul.x, t.y, fmaf(-uy, t.x, y.y));
        }
        XF[adr] = y;
        __syncthreads();
    }
}

__global__ __launch_bounds__(256) void k_inv_rows_bias(const float2* __restrict__ XF,
                                                       const float* __restrict__ biasp,
                                                       float* __restrict__ out) {
    __shared__ float2 buf[4][HW];
    int wave = threadIdx.x >> 6, lane = threadIdx.x & 63;
    long row = (long)blockIdx.x * 4 + wave;     // (b,o,h)
    int o = (int)((row >> 7) & 31);
    float bp = biasp[o];
    long base = row * HW;
    float2* d = buf[wave];
    d[lane]      = XF[base + lane];
    d[lane + 64] = XF[base + lane + 64];
    __syncthreads();
    fft128(d, lane, +1.f);
    const float sc = 1.0f / 128.0f;
    out[base + lane]      = d[lane].x * sc + bp;
    out[base + lane + 64] = d[lane + 64].x * sc + bp;
}

__global__ __launch_bounds__(256) void k_dist(const float* __restrict__ distP,
                                              float* __restrict__ out) {
    __shared__ float sh[256];
    float acc = 0.f;
    for (int i = threadIdx.x; i < NPROB; i += 256) acc += distP[i];
    sh[threadIdx.x] = acc;
    __syncthreads();
    for (int s = 128; s >= 1; s >>= 1) {
        if (threadIdx.x < s) sh[threadIdx.x] += sh[threadIdx.x + s];
        __syncthreads();
    }
    if (threadIdx.x == 0) out[(size_t)NB * NCH * NPIX] = sqrtf(sh[0]);
}

extern "C" void kernel_launch(void* const* d_in, const int* in_sizes, int n_in,
                              void* d_out, int out_size, void* d_ws, size_t ws_size,
                              hipStream_t stream) {
    (void)in_sizes; (void)n_in; (void)out_size; (void)ws_size;
    const float* x    = (const float*)d_in[0];
    const float* ker  = (const float*)d_in[1];
    const float* bias = (const float*)d_in[2];
    float* out = (float*)d_out;

    // ws: XF complex [16][32][128][128] (64 MiB) | distP [8194] | biasp [32]
    float2* XF   = (float2*)d_ws;
    float* distP = (float*)((char*)d_ws + (size_t)NB * NCH * NPIX * sizeof(float2));
    float* biasp = distP + NPROB;
    // U scratch in the tail of d_out (33.6 MB at +96 MB; overwritten later by
    // k_inv_rows_bias, which runs after k_apply has consumed it — stream order).
    float2* Uws = (float2*)((char*)d_out + ((size_t)96 << 20));

    int rows = NB * NCH * HW;   // 65536
    k_fwd_rows<<<dim3(rows / 4), dim3(256), 0, stream>>>(x, XF);
    k_cols<<<dim3(NB * NCH * 8), dim3(256), 0, stream>>>(XF, -1.f);
    k_eig4<<<dim3(NPROB), dim3(64), 0, stream>>>(ker, bias, Uws, distP, biasp);
    k_apply<<<dim3(NPIX / 8), dim3(256), 0, stream>>>(Uws, XF);
    k_cols<<<dim3(NB * NCH * 8), dim3(256), 0, stream>>>(XF, +1.f);
    k_inv_rows_bias<<<dim3(rows / 4), dim3(256), 0, stream>>>(XF, biasp, out);
    k_dist<<<dim3(1), dim3(256), 0, stream>>>(distP, out);
}

// Round 10
// 1012.385 us; speedup vs baseline: 1.1254x; 1.1254x over previous
//
#include <hip/hip_runtime.h>
#include <math.h>

#define NCH 32
#define NB  16
#define HW  128
#define NPIX (HW*HW)
#define NPROB 8194

typedef float v2f __attribute__((ext_vector_type(2)));

// DPP ctrl encodings: quad_perm xor1/2/3, row_half_mirror (xor7), row_mirror (xor15)
#define DPP_XOR1  0xB1
#define DPP_XOR2  0x4E
#define DPP_XOR3  0x1B
#define DPP_XOR7  0x141
#define DPP_XOR15 0x140

template<int CTRL>
__device__ __forceinline__ float fdpp(float v) {
    return __int_as_float(__builtin_amdgcn_mov_dpp(__float_as_int(v), CTRL, 0xF, 0xF, false));
}

__device__ __forceinline__ float2 cmulf(float2 a, float2 b) {
    return make_float2(a.x*b.x - a.y*b.y, a.x*b.y + a.y*b.x);
}
__device__ __forceinline__ int rev7(int i) { return (int)(__brev((unsigned)i) >> 25); }
// HW trig: input in revolutions (angle/2pi). Exact for dyadic-rational inputs.
__device__ __forceinline__ float hw_sin(float rev) { return __builtin_amdgcn_sinf(rev); }
__device__ __forceinline__ float hw_cos(float rev) { return __builtin_amdgcn_cosf(rev); }

// ---- packed fp32 helpers (CDNA v_pk_*) ----
__device__ __forceinline__ v2f pk_fma(v2f a, v2f b, v2f c) {
    v2f d;
    asm("v_pk_fma_f32 %0, %1, %2, %3" : "=v"(d) : "v"(a), "v"(b), "v"(c));
    return d;
}
__device__ __forceinline__ v2f pk_fma_swap1(v2f a, v2f b, v2f c) {
    v2f d;
    asm("v_pk_fma_f32 %0, %1, %2, %3 op_sel:[0,1,0] op_sel_hi:[1,0,1]"
        : "=v"(d) : "v"(a), "v"(b), "v"(c));
    return d;
}
__device__ __forceinline__ v2f pk_mul_swap1(v2f a, v2f b) {
    v2f d;
    asm("v_pk_mul_f32 %0, %1, %2 op_sel:[0,1] op_sel_hi:[1,0]"
        : "=v"(d) : "v"(a), "v"(b));
    return d;
}

// 128-point radix-2 DIF FFT in LDS; 64 lanes cooperate on one transform.
__device__ void fft128(float2* d, int lane, float sign) {
    for (int span = 64; span >= 1; span >>= 1) {
        int k = lane & (span - 1);
        int base = ((lane & ~(span - 1)) << 1) | k;
        float2 a = d[base];
        float2 b = d[base + span];
        float2 su = make_float2(a.x + b.x, a.y + b.y);
        float2 df = make_float2(a.x - b.x, a.y - b.y);
        float rev = (float)k / (float)(2 * span);
        float cw = hw_cos(rev);
        float sw = sign * hw_sin(rev);
        d[base] = su;
        d[base + span] = cmulf(df, make_float2(cw, sw));
        __syncthreads();
    }
    float2 v0 = d[rev7(lane)];
    float2 v1 = d[rev7(lane + 64)];
    __syncthreads();
    d[lane] = v0;
    d[lane + 64] = v1;
    __syncthreads();
}

__global__ __launch_bounds__(256) void k_fwd_rows(const float* __restrict__ x,
                                                  float2* __restrict__ XF) {
    __shared__ float2 buf[4][HW];
    int wave = threadIdx.x >> 6, lane = threadIdx.x & 63;
    long row = (long)blockIdx.x * 4 + wave;
    long base = row * HW;
    const float sc = 1.0f / 128.0f;
    float2* d = buf[wave];
    d[lane]      = make_float2(x[base + lane] * sc, 0.f);
    d[lane + 64] = make_float2(x[base + lane + 64] * sc, 0.f);
    __syncthreads();
    fft128(d, lane, -1.f);
    XF[base + lane]      = d[lane];
    XF[base + lane + 64] = d[lane + 64];
}

__global__ __launch_bounds__(256) void k_cols(float2* __restrict__ XF, float sign) {
    __shared__ float2 tile[HW][17];
    int img = blockIdx.x >> 3;
    int w0  = (blockIdx.x & 7) << 4;
    long base = (long)img * NPIX + w0;
    int tid = threadIdx.x;
    for (int it = 0; it < 8; ++it) {
        int flat = it * 256 + tid;
        int h = flat >> 4, c = flat & 15;
        tile[h][c] = XF[base + (long)h * HW + c];
    }
    __syncthreads();
    for (int span = 64; span >= 1; span >>= 1) {
        for (int it = 0; it < 4; ++it) {
            int idx = it * 256 + tid;
            int j = idx >> 4, c = idx & 15;
            int k = j & (span - 1);
            int bidx = ((j & ~(span - 1)) << 1) | k;
            float2 a = tile[bidx][c], b = tile[bidx + span][c];
            float2 su = make_float2(a.x + b.x, a.y + b.y);
            float2 df = make_float2(a.x - b.x, a.y - b.y);
            float rev = (float)k / (float)(2 * span);
            float cw = hw_cos(rev);
            float sw = sign * hw_sin(rev);
            tile[bidx][c] = su;
            tile[bidx + span][c] = cmulf(df, make_float2(cw, sw));
        }
        __syncthreads();
    }
    float2 v[8];
    for (int it = 0; it < 8; ++it) {
        int flat = it * 256 + tid;
        int h = flat >> 4, c = flat & 15;
        v[it] = tile[rev7(h)][c];
    }
    __syncthreads();
    for (int it = 0; it < 8; ++it) {
        int flat = it * 256 + tid;
        int h = flat >> 4, c = flat & 15;
        tile[h][c] = v[it];
    }
    __syncthreads();
    for (int it = 0; it < 8; ++it) {
        int flat = it * 256 + tid;
        int h = flat >> 4, c = flat & 15;
        XF[base + (long)h * HW + c] = tile[h][c];
    }
}

__device__ __forceinline__ void prob_to_hw(int gp, int& h, int& w) {
    if (gp < 8064)      { h = 1 + (gp >> 7); w = gp & 127; }
    else if (gp < 8129) { h = 0;  w = gp - 8064; }
    else                { h = 64; w = gp - 8129; }
}

// pixel (h,w) -> (representative problem gp, conjugate flag)
__device__ __forceinline__ void pix_to_prob(int h, int w, int& gp, bool& cj) {
    if (h >= 1 && h <= 63)      { gp = (h - 1) * 128 + w; cj = false; }
    else if (h >= 65)           { gp = (127 - h) * 128 + ((128 - w) & 127); cj = true; }
    else if (h == 0)            { if (w <= 64) { gp = 8064 + w; cj = false; }
                                  else        { gp = 8064 + 128 - w; cj = true; } }
    else                        { if (w <= 64) { gp = 8129 + w; cj = false; }
                                  else        { gp = 8129 + 128 - w; cj = true; } }
}

// build rows [rh*16, rh*16+16) of K column `col`: b[j] = K_{rh*16+j, col}(h,w)
__device__ __forceinline__ void build_kcol_half(const float* __restrict__ ker,
                                                int h, int w, int col, int rh, v2f* b) {
    float twr[9], twi[9];
    #pragma unroll
    for (int u = 0; u < 3; ++u)
        #pragma unroll
        for (int v = 0; v < 3; ++v) {
            int idx = (h * u + w * v) & 127;
            float rev = (float)idx * (1.0f / 128.0f);
            twr[u * 3 + v] =  hw_cos(rev);
            twi[u * 3 + v] = -hw_sin(rev);
        }
    #pragma unroll
    for (int j = 0; j < 16; ++j) {
        int o = (rh << 4) + j;
        const float* kp = ker + (size_t)(o * NCH + col) * 9;
        float ar = 0.f, ai = 0.f;
        #pragma unroll
        for (int t = 0; t < 9; ++t) { float kv = kp[t]; ar = fmaf(kv, twr[t], ar); ai = fmaf(kv, twi[t], ai); }
        b[j].x = ar; b[j].y = ai;
    }
}

__device__ __forceinline__ float halfsum(float v) {
    v += __shfl_xor(v, 1);  v += __shfl_xor(v, 2);  v += __shfl_xor(v, 4);
    v += __shfl_xor(v, 8);  v += __shfl_xor(v, 16);
    return v;
}
__device__ __forceinline__ float wsum64(float v) {
    v = halfsum(v); v += __shfl_xor(v, 32);
    return v;
}

// Common Jacobi round tail: Gram from cached F, coefficients, packed rotation.
__device__ __forceinline__ void jrot(v2f b[16], const v2f* F, float nf,
                                     float& cn, float& offacc, bool isP) {
    // packed partial Gram: acc1 = (Σ bx*fx, Σ by*fy) ; acc2 = (Σ bx*fy, Σ by*fx)
    v2f acc1 = (v2f)(0.f), acc2 = (v2f)(0.f);
    #pragma unroll
    for (int i = 0; i < 16; ++i) {
        acc1 = pk_fma(b[i], F[i], acc1);
        acc2 = pk_fma_swap1(b[i], F[i], acc2);
    }
    float greP = acc1.x + acc1.y;
    float gimP = isP ? (acc2.x - acc2.y) : (acc2.y - acc2.x);
    float gre = greP + __shfl_xor(greP, 32, 64);
    float gim = gimP + __shfl_xor(gimP, 32, 64);
    float app = isP ? cn : nf;
    float aqq = isP ? nf : cn;
    float n2 = gre * gre + gim * gim;
    offacc += n2;

    bool doRot = (n2 > 1e-24f * app * aqq) && (n2 > 1e-36f);
    if (__ballot(doRot)) {
        float ad  = sqrtf(n2);
        float tau = (aqq - app) / (2.f * ad);
        float tt  = (tau >= 0.f ? 1.f : -1.f) / (fabsf(tau) + sqrtf(fmaf(tau, tau, 1.f)));
        float cc  = rsqrtf(fmaf(tt, tt, 1.f));
        float sg  = tt * cc / ad;
        float ssx = sg * gre, ssy = sg * gim;
        float gx  = isP ? -ssx : ssx;
        float gy  = ssy;
        float dlt = tt * ad;               // diagonal shift
        if (!doRot) { cc = 1.f; gx = 0.f; gy = 0.f; dlt = 0.f; }
        v2f ccv = (v2f)(cc);
        v2f gxv = (v2f)(gx);
        v2f gyv; gyv.x = -gy; gyv.y = gy;
        #pragma unroll
        for (int i = 0; i < 16; ++i) {
            v2f t = pk_mul_swap1(gyv, F[i]);
            t = pk_fma(gxv, F[i], t);
            b[i] = pk_fma(ccv, b[i], t);
        }
        cn += isP ? -dlt : dlt;
    }
}

// DPP round: partner exchange on VALU pipe (zero DS traffic)
template<int CTRL>
__device__ __forceinline__ void round_dpp(v2f b[16], float& cn, float& offacc,
                                          int col, int m) {
    bool isP = col < (col ^ m);
    v2f F[16];
    #pragma unroll
    for (int i = 0; i < 16; ++i) {
        F[i].x = fdpp<CTRL>(b[i].x);
        F[i].y = fdpp<CTRL>(b[i].y);
    }
    float nf = fdpp<CTRL>(cn);
    jrot(b, F, nf, cn, offacc, isP);
}

// DS round: runtime mask via shfl_xor
__device__ __forceinline__ void round_ds(v2f b[16], float& cn, float& offacc,
                                         int col, int m) {
    bool isP = col < (col ^ m);
    v2f F[16];
    #pragma unroll
    for (int i = 0; i < 16; ++i) {
        F[i].x = __shfl_xor(b[i].x, m, 64);
        F[i].y = __shfl_xor(b[i].y, m, 64);
    }
    float nf = __shfl_xor(cn, m, 64);
    jrot(b, F, nf, cn, offacc, isP);
}

// One-sided Jacobi SVD per pixel. ONE problem per 64-thread block (1 wave).
// lane (rh,col) owns rows [rh*16,rh*16+16) of column col. XOR-pair ordering;
// masks {1,2,3,7,15} exchanged via DPP (VALU pipe), the rest via DS.
__global__ __launch_bounds__(64, 1) void k_eig5(
    const float* __restrict__ ker, const float* __restrict__ bias,
    float2* __restrict__ Uws, float* __restrict__ distP, float* __restrict__ biasp)
{
    __shared__ float2 U[16][33];      // selected columns, transposed access

    int l64  = threadIdx.x & 63;
    int rh   = l64 >> 5;
    int col  = l64 & 31;
    int sbase = rh << 5;

    int gp = blockIdx.x;              // grid == NPROB exactly
    int h, w; prob_to_hw(gp, h, w);
    int hc = (128 - h) & 127, wc = (128 - w) & 127;
    bool self = (hc == h && wc == w);

    v2f b[16];
    build_kcol_half(ker, h, w, col, rh, b);

    // tracked column norm^2 (identical across rh halves by construction)
    float cn;
    {
        float nr = 0.f;
        #pragma unroll
        for (int i = 0; i < 16; ++i) nr = fmaf(b[i].x, b[i].x, fmaf(b[i].y, b[i].y, nr));
        cn = nr + __shfl_xor(nr, 32, 64);
    }

    // ---- one-sided Jacobi: 31 XOR masks per sweep (DPP-able ones first) ----
    for (int sweep = 0; sweep < 6; ++sweep) {
        float offacc = 0.f;
        round_dpp<DPP_XOR1 >(b, cn, offacc, col, 1);
        round_dpp<DPP_XOR2 >(b, cn, offacc, col, 2);
        round_dpp<DPP_XOR3 >(b, cn, offacc, col, 3);
        round_dpp<DPP_XOR7 >(b, cn, offacc, col, 7);
        round_dpp<DPP_XOR15>(b, cn, offacc, col, 15);
        for (int m = 4; m < 32; ++m) {
            if (m == 7 || m == 15) continue;
            round_ds(b, cn, offacc, col, m);
        }
        // convergence: sum|g|^2 (pair-double-counted) <= 1e-6 * sum(sigma^4)
        float dg   = halfsum(cn * cn);
        float offT = halfsum(offacc);
        if (!__ballot(offT > 1e-6f * dg)) break;
    }

    // ---- top-16 selection by EXACT column norm; write normalized U ----
    float nr = 0.f;
    #pragma unroll
    for (int i = 0; i < 16; ++i) nr = fmaf(b[i].x, b[i].x, fmaf(b[i].y, b[i].y, nr));
    float nrF = nr + __shfl_xor(nr, 32, 64);
    int rank = 0;
    #pragma unroll
    for (int k = 0; k < 32; ++k) {
        float nk = __shfl(nrF, k, 64);
        if (nk > nrF || (nk == nrF && k < col)) ++rank;
    }
    bool sel = rank < 16;
    unsigned long long ball = __ballot(sel);
    unsigned cmask = (unsigned)(ball & 0xFFFFFFFFull);
    int rsel = __popc(cmask & ((1u << col) - 1u));
    float rin = rsqrtf(fmaxf(nrF, 1e-30f));
    if (sel) {
        #pragma unroll
        for (int j = 0; j < 16; ++j) {
            float2 uv = make_float2(b[j].x * rin, b[j].y * rin);
            U[rsel][(rh << 4) + j] = uv;
            Uws[((size_t)gp * 16 + rsel) * 32 + (rh << 4) + j] = uv;
        }
    }
    asm volatile("s_waitcnt lgkmcnt(0)" ::: "memory");
    __builtin_amdgcn_sched_barrier(0);

    // ---- dist: ||K-P||^2 = ||K||^2 - 2 Re tr(K^H P) + 16 ----
    build_kcol_half(ker, h, w, col, rh, b);
    float kn = 0.f;
    #pragma unroll
    for (int j = 0; j < 16; ++j) kn = fmaf(b[j].x, b[j].x, fmaf(b[j].y, b[j].y, kn));
    float knt = wsum64(kn);
    float tr = 0.f;                            // both rh halves count -> 2x
    #pragma unroll
    for (int m = 0; m < 16; ++m) {
        float2 acc = make_float2(0.f, 0.f);
        #pragma unroll
        for (int j = 0; j < 16; ++j) {
            float2 um = U[m][(rh << 4) + j];
            acc.x = fmaf(b[j].x, um.x, fmaf( b[j].y, um.y, acc.x));
            acc.y = fmaf(b[j].x, um.y, fmaf(-b[j].y, um.x, acc.y));
        }
        acc.x += __shfl_xor(acc.x, 32, 64);
        acc.y += __shfl_xor(acc.y, 32, 64);
        float2 w0 = U[m][col];
        tr = fmaf(w0.x, acc.x, fmaf(w0.y, acc.y, tr));
    }
    float trt = wsum64(tr);                    // = 2 * Re tr(K^H P)
    if (l64 == 0) {
        float d2 = knt - trt + 16.f;
        distP[gp] = (self ? 1.f : 2.f) * d2;
    }

    // ---- bias correction at DC pixel (gp==8064 -> (h,w)=(0,0)) ----
    if (gp == 8064) {
        int mmode = col & 15;
        float2 d = make_float2(0.f, 0.f);
        #pragma unroll
        for (int j = 0; j < 16; ++j) {
            int i = (rh << 4) + j;
            float bv = bias[i];
            float2 ul = U[mmode][i];
            d.x = fmaf(ul.x, bv, d.x);
            d.y = fmaf(-ul.y, bv, d.y);
        }
        d.x += __shfl_xor(d.x, 32, 64);
        d.y += __shfl_xor(d.y, 32, 64);
        float racc = 0.f;
        #pragma unroll
        for (int mm = 0; mm < 16; ++mm) {
            float dx = __shfl(d.x, sbase + mm, 64);
            float dy = __shfl(d.y, sbase + mm, 64);
            float2 ul = U[mm][col];
            racc = fmaf(ul.x, dx, fmaf(-ul.y, dy, racc));
        }
        if (rh == 0) biasp[col] = bias[col] - racc;
    }
}

// Apply y_f = conj(P) x_f per pixel, rank-16 form. 8 consecutive pixels per
// block (one 64B line per (b,c) row -> coalesced). U staged in LDS.
__global__ __launch_bounds__(256) void k_apply(const float2* __restrict__ Uws,
                                               float2* __restrict__ XF)
{
    __shared__ float2 Us[16][33][9];   // [m][i][slot] (pads kill 8-way conflicts)
    __shared__ float2 xs[32][9];       // [c][slot]
    __shared__ float2 ts[16][9];       // [m][slot]

    int tid = threadIdx.x;
    int pb = blockIdx.x * 8;
    int h = pb >> 7, w0 = pb & 127;

    // --- stage U for the 8 pixels of this block ---
    {
        int slot = tid >> 5, t5 = tid & 31;
        int gp; bool cj;
        pix_to_prob(h, w0 + slot, gp, cj);
        size_t gbase = (size_t)gp * 512 + (size_t)t5 * 16;
        #pragma unroll
        for (int j = 0; j < 16; ++j) {
            int e = t5 * 16 + j;
            Us[e >> 5][e & 31][slot] = Uws[gbase + j];
        }
    }
    __syncthreads();

    int c = tid >> 3, ws = tid & 7;
    int gp; bool cj;
    pix_to_prob(h, w0 + ws, gp, cj);
    float sgn = cj ? -1.f : 1.f;
    long pbase = (long)h * 128 + (w0 + ws);

    for (int bb = 0; bb < NB; ++bb) {
        long adr = ((long)(bb * NCH + c)) * NPIX + pbase;
        xs[c][ws] = XF[adr];
        __syncthreads();
        if (c < 16) {
            float2 t = make_float2(0.f, 0.f);
            #pragma unroll
            for (int i = 0; i < 32; ++i) {
                float2 ul = Us[c][i][ws];
                float uy = sgn * ul.y;
                float2 xr = xs[i][ws];
                t.x = fmaf(ul.x, xr.x, fmaf(-uy, xr.y, t.x));
                t.y = fmaf(ul.x, xr.y, fmaf( uy, xr.x, t.y));
            }
            ts[c][ws] = t;
        }
        __syncthreads();
        float2 y = make_float2(0.f, 0.f);
        #pragma unroll
        for (int m = 0; m < 16; ++m) {
            float2 ul = Us[m][c][ws];
            float uy = sgn * ul.y;
            float2 t = ts[m][ws];
            y.x = fmaf(ul.x, t.x, fmaf( uy, t.y, y.x));
            y.y = fmaf(ul.x, t.y, fmaf(-uy, t.x, y.y));
        }
        XF[adr] = y;
        __syncthreads();
    }
}

__global__ __launch_bounds__(256) void k_inv_rows_bias(const float2* __restrict__ XF,
                                                       const float* __restrict__ biasp,
                                                       float* __restrict__ out) {
    __shared__ float2 buf[4][HW];
    int wave = threadIdx.x >> 6, lane = threadIdx.x & 63;
    long row = (long)blockIdx.x * 4 + wave;     // (b,o,h)
    int o = (int)((row >> 7) & 31);
    float bp = biasp[o];
    long base = row * HW;
    float2* d = buf[wave];
    d[lane]      = XF[base + lane];
    d[lane + 64] = XF[base + lane + 64];
    __syncthreads();
    fft128(d, lane, +1.f);
    const float sc = 1.0f / 128.0f;
    out[base + lane]      = d[lane].x * sc + bp;
    out[base + lane + 64] = d[lane + 64].x * sc + bp;
}

__global__ __launch_bounds__(256) void k_dist(const float* __restrict__ distP,
                                              float* __restrict__ out) {
    __shared__ float sh[256];
    float acc = 0.f;
    for (int i = threadIdx.x; i < NPROB; i += 256) acc += distP[i];
    sh[threadIdx.x] = acc;
    __syncthreads();
    for (int s = 128; s >= 1; s >>= 1) {
        if (threadIdx.x < s) sh[threadIdx.x] += sh[threadIdx.x + s];
        __syncthreads();
    }
    if (threadIdx.x == 0) out[(size_t)NB * NCH * NPIX] = sqrtf(sh[0]);
}

extern "C" void kernel_launch(void* const* d_in, const int* in_sizes, int n_in,
                              void* d_out, int out_size, void* d_ws, size_t ws_size,
                              hipStream_t stream) {
    (void)in_sizes; (void)n_in; (void)out_size; (void)ws_size;
    const float* x    = (const float*)d_in[0];
    const float* ker  = (const float*)d_in[1];
    const float* bias = (const float*)d_in[2];
    float* out = (float*)d_out;

    // ws: XF complex [16][32][128][128] (64 MiB) | distP [8194] | biasp [32]
    float2* XF   = (float2*)d_ws;
    float* distP = (float*)((char*)d_ws + (size_t)NB * NCH * NPIX * sizeof(float2));
    float* biasp = distP + NPROB;
    // U scratch in the tail of d_out (33.6 MB at +96 MB; overwritten later by
    // k_inv_rows_bias, which runs after k_apply has consumed it — stream order).
    float2* Uws = (float2*)((char*)d_out + ((size_t)96 << 20));

    int rows = NB * NCH * HW;   // 65536
    k_fwd_rows<<<dim3(rows / 4), dim3(256), 0, stream>>>(x, XF);
    k_cols<<<dim3(NB * NCH * 8), dim3(256), 0, stream>>>(XF, -1.f);
    k_eig5<<<dim3(NPROB), dim3(64), 0, stream>>>(ker, bias, Uws, distP, biasp);
    k_apply<<<dim3(NPIX / 8), dim3(256), 0, stream>>>(Uws, XF);
    k_cols<<<dim3(NB * NCH * 8), dim3(256), 0, stream>>>(XF, +1.f);
    k_inv_rows_bias<<<dim3(rows / 4), dim3(256), 0, stream>>>(XF, biasp, out);
    k_dist<<<dim3(1), dim3(256), 0, stream>>>(distP, out);
}

// Round 11
// 1005.654 us; speedup vs baseline: 1.1330x; 1.0067x over previous
//
#include <hip/hip_runtime.h>
#include <math.h>

#define NCH 32
#define NB  16
#define HW  128
#define NPIX (HW*HW)
#define NPROB 8194

typedef float v2f __attribute__((ext_vector_type(2)));

// DPP ctrl encodings: quad_perm xor1/2/3, row_half_mirror (xor7), row_mirror (xor15)
#define DPP_XOR1  0xB1
#define DPP_XOR2  0x4E
#define DPP_XOR3  0x1B
#define DPP_XOR7  0x141
#define DPP_XOR15 0x140

template<int CTRL>
__device__ __forceinline__ float fdpp(float v) {
    return __int_as_float(__builtin_amdgcn_mov_dpp(__float_as_int(v), CTRL, 0xF, 0xF, false));
}

__device__ __forceinline__ float2 cmulf(float2 a, float2 b) {
    return make_float2(a.x*b.x - a.y*b.y, a.x*b.y + a.y*b.x);
}
__device__ __forceinline__ int rev7(int i) { return (int)(__brev((unsigned)i) >> 25); }
// HW trig: input in revolutions (angle/2pi). Exact for dyadic-rational inputs.
__device__ __forceinline__ float hw_sin(float rev) { return __builtin_amdgcn_sinf(rev); }
__device__ __forceinline__ float hw_cos(float rev) { return __builtin_amdgcn_cosf(rev); }

// ---- packed fp32 helpers (CDNA v_pk_*) ----
__device__ __forceinline__ v2f pk_fma(v2f a, v2f b, v2f c) {
    v2f d;
    asm("v_pk_fma_f32 %0, %1, %2, %3" : "=v"(d) : "v"(a), "v"(b), "v"(c));
    return d;
}
__device__ __forceinline__ v2f pk_fma_swap1(v2f a, v2f b, v2f c) {
    v2f d;
    asm("v_pk_fma_f32 %0, %1, %2, %3 op_sel:[0,1,0] op_sel_hi:[1,0,1]"
        : "=v"(d) : "v"(a), "v"(b), "v"(c));
    return d;
}
__device__ __forceinline__ v2f pk_mul_swap1(v2f a, v2f b) {
    v2f d;
    asm("v_pk_mul_f32 %0, %1, %2 op_sel:[0,1] op_sel_hi:[1,0]"
        : "=v"(d) : "v"(a), "v"(b));
    return d;
}

// 128-point radix-2 DIF FFT in LDS; 64 lanes cooperate on one transform.
__device__ void fft128(float2* d, int lane, float sign) {
    for (int span = 64; span >= 1; span >>= 1) {
        int k = lane & (span - 1);
        int base = ((lane & ~(span - 1)) << 1) | k;
        float2 a = d[base];
        float2 b = d[base + span];
        float2 su = make_float2(a.x + b.x, a.y + b.y);
        float2 df = make_float2(a.x - b.x, a.y - b.y);
        float rev = (float)k / (float)(2 * span);
        float cw = hw_cos(rev);
        float sw = sign * hw_sin(rev);
        d[base] = su;
        d[base + span] = cmulf(df, make_float2(cw, sw));
        __syncthreads();
    }
    float2 v0 = d[rev7(lane)];
    float2 v1 = d[rev7(lane + 64)];
    __syncthreads();
    d[lane] = v0;
    d[lane + 64] = v1;
    __syncthreads();
}

__global__ __launch_bounds__(256) void k_fwd_rows(const float* __restrict__ x,
                                                  float2* __restrict__ XF) {
    __shared__ float2 buf[4][HW];
    int wave = threadIdx.x >> 6, lane = threadIdx.x & 63;
    long row = (long)blockIdx.x * 4 + wave;
    long base = row * HW;
    const float sc = 1.0f / 128.0f;
    float2* d = buf[wave];
    d[lane]      = make_float2(x[base + lane] * sc, 0.f);
    d[lane + 64] = make_float2(x[base + lane + 64] * sc, 0.f);
    __syncthreads();
    fft128(d, lane, -1.f);
    XF[base + lane]      = d[lane];
    XF[base + lane + 64] = d[lane + 64];
}

__global__ __launch_bounds__(256) void k_cols(float2* __restrict__ XF, float sign) {
    __shared__ float2 tile[HW][17];
    int img = blockIdx.x >> 3;
    int w0  = (blockIdx.x & 7) << 4;
    long base = (long)img * NPIX + w0;
    int tid = threadIdx.x;
    for (int it = 0; it < 8; ++it) {
        int flat = it * 256 + tid;
        int h = flat >> 4, c = flat & 15;
        tile[h][c] = XF[base + (long)h * HW + c];
    }
    __syncthreads();
    for (int span = 64; span >= 1; span >>= 1) {
        for (int it = 0; it < 4; ++it) {
            int idx = it * 256 + tid;
            int j = idx >> 4, c = idx & 15;
            int k = j & (span - 1);
            int bidx = ((j & ~(span - 1)) << 1) | k;
            float2 a = tile[bidx][c], b = tile[bidx + span][c];
            float2 su = make_float2(a.x + b.x, a.y + b.y);
            float2 df = make_float2(a.x - b.x, a.y - b.y);
            float rev = (float)k / (float)(2 * span);
            float cw = hw_cos(rev);
            float sw = sign * hw_sin(rev);
            tile[bidx][c] = su;
            tile[bidx + span][c] = cmulf(df, make_float2(cw, sw));
        }
        __syncthreads();
    }
    float2 v[8];
    for (int it = 0; it < 8; ++it) {
        int flat = it * 256 + tid;
        int h = flat >> 4, c = flat & 15;
        v[it] = tile[rev7(h)][c];
    }
    __syncthreads();
    for (int it = 0; it < 8; ++it) {
        int flat = it * 256 + tid;
        int h = flat >> 4, c = flat & 15;
        tile[h][c] = v[it];
    }
    __syncthreads();
    for (int it = 0; it < 8; ++it) {
        int flat = it * 256 + tid;
        int h = flat >> 4, c = flat & 15;
        XF[base + (long)h * HW + c] = tile[h][c];
    }
}

__device__ __forceinline__ void prob_to_hw(int gp, int& h, int& w) {
    if (gp < 8064)      { h = 1 + (gp >> 7); w = gp & 127; }
    else if (gp < 8129) { h = 0;  w = gp - 8064; }
    else                { h = 64; w = gp - 8129; }
}

// pixel (h,w) -> (representative problem gp, conjugate flag)
__device__ __forceinline__ void pix_to_prob(int h, int w, int& gp, bool& cj) {
    if (h >= 1 && h <= 63)      { gp = (h - 1) * 128 + w; cj = false; }
    else if (h >= 65)           { gp = (127 - h) * 128 + ((128 - w) & 127); cj = true; }
    else if (h == 0)            { if (w <= 64) { gp = 8064 + w; cj = false; }
                                  else        { gp = 8064 + 128 - w; cj = true; } }
    else                        { if (w <= 64) { gp = 8129 + w; cj = false; }
                                  else        { gp = 8129 + 128 - w; cj = true; } }
}

// build rows [rh*16, rh*16+16) of K column `col`: b[j] = K_{rh*16+j, col}(h,w)
__device__ __forceinline__ void build_kcol_half(const float* __restrict__ ker,
                                                int h, int w, int col, int rh, v2f* b) {
    float twr[9], twi[9];
    #pragma unroll
    for (int u = 0; u < 3; ++u)
        #pragma unroll
        for (int v = 0; v < 3; ++v) {
            int idx = (h * u + w * v) & 127;
            float rev = (float)idx * (1.0f / 128.0f);
            twr[u * 3 + v] =  hw_cos(rev);
            twi[u * 3 + v] = -hw_sin(rev);
        }
    #pragma unroll
    for (int j = 0; j < 16; ++j) {
        int o = (rh << 4) + j;
        const float* kp = ker + (size_t)(o * NCH + col) * 9;
        float ar = 0.f, ai = 0.f;
        #pragma unroll
        for (int t = 0; t < 9; ++t) { float kv = kp[t]; ar = fmaf(kv, twr[t], ar); ai = fmaf(kv, twi[t], ai); }
        b[j].x = ar; b[j].y = ai;
    }
}

__device__ __forceinline__ float halfsum(float v) {
    v += __shfl_xor(v, 1);  v += __shfl_xor(v, 2);  v += __shfl_xor(v, 4);
    v += __shfl_xor(v, 8);  v += __shfl_xor(v, 16);
    return v;
}
__device__ __forceinline__ float wsum64(float v) {
    v = halfsum(v); v += __shfl_xor(v, 32);
    return v;
}

// Common Jacobi round tail: Gram from cached F, coefficients, packed rotation.
__device__ __forceinline__ void jrot(v2f b[16], const v2f* F, float nf,
                                     float& cn, float& offacc, bool isP) {
    // packed partial Gram: acc1 = (Σ bx*fx, Σ by*fy) ; acc2 = (Σ bx*fy, Σ by*fx)
    v2f acc1 = (v2f)(0.f), acc2 = (v2f)(0.f);
    #pragma unroll
    for (int i = 0; i < 16; ++i) {
        acc1 = pk_fma(b[i], F[i], acc1);
        acc2 = pk_fma_swap1(b[i], F[i], acc2);
    }
    float greP = acc1.x + acc1.y;
    float gimP = isP ? (acc2.x - acc2.y) : (acc2.y - acc2.x);
    float gre = greP + __shfl_xor(greP, 32, 64);
    float gim = gimP + __shfl_xor(gimP, 32, 64);
    float app = isP ? cn : nf;
    float aqq = isP ? nf : cn;
    float n2 = gre * gre + gim * gim;
    offacc += n2;

    // skip fully-converged rotations (relative |g| < 1e-7) wave-uniformly
    bool doRot = (n2 > 1e-14f * app * aqq) && (n2 > 1e-36f);
    if (__ballot(doRot)) {
        float ad  = sqrtf(n2);
        float tau = (aqq - app) / (2.f * ad);
        float tt  = (tau >= 0.f ? 1.f : -1.f) / (fabsf(tau) + sqrtf(fmaf(tau, tau, 1.f)));
        float cc  = rsqrtf(fmaf(tt, tt, 1.f));
        float sg  = tt * cc / ad;
        float ssx = sg * gre, ssy = sg * gim;
        float gx  = isP ? -ssx : ssx;
        float gy  = ssy;
        float dlt = tt * ad;               // diagonal shift
        if (!doRot) { cc = 1.f; gx = 0.f; gy = 0.f; dlt = 0.f; }
        v2f ccv = (v2f)(cc);
        v2f gxv = (v2f)(gx);
        v2f gyv; gyv.x = -gy; gyv.y = gy;
        #pragma unroll
        for (int i = 0; i < 16; ++i) {
            v2f t = pk_mul_swap1(gyv, F[i]);
            t = pk_fma(gxv, F[i], t);
            b[i] = pk_fma(ccv, b[i], t);
        }
        cn += isP ? -dlt : dlt;
    }
}

// DPP round: partner exchange on VALU pipe (zero DS traffic)
template<int CTRL>
__device__ __forceinline__ void round_dpp(v2f b[16], float& cn, float& offacc,
                                          int col, int m) {
    bool isP = col < (col ^ m);
    v2f F[16];
    #pragma unroll
    for (int i = 0; i < 16; ++i) {
        F[i].x = fdpp<CTRL>(b[i].x);
        F[i].y = fdpp<CTRL>(b[i].y);
    }
    float nf = fdpp<CTRL>(cn);
    jrot(b, F, nf, cn, offacc, isP);
}

// DS round: runtime mask via shfl_xor
__device__ __forceinline__ void round_ds(v2f b[16], float& cn, float& offacc,
                                         int col, int m) {
    bool isP = col < (col ^ m);
    v2f F[16];
    #pragma unroll
    for (int i = 0; i < 16; ++i) {
        F[i].x = __shfl_xor(b[i].x, m, 64);
        F[i].y = __shfl_xor(b[i].y, m, 64);
    }
    float nf = __shfl_xor(cn, m, 64);
    jrot(b, F, nf, cn, offacc, isP);
}

// One-sided Jacobi SVD per pixel. 2 problems per 128-thread block (2 independent
// waves -> tests the resident-wave cap; no __syncthreads anywhere).
// lane (rh,col) owns rows [rh*16,rh*16+16) of column col. XOR-pair ordering;
// masks {1,2,3,7,15} via DPP (VALU pipe), the rest via DS.
__global__ __launch_bounds__(128, 1) void k_eig6(
    const float* __restrict__ ker, const float* __restrict__ bias,
    float2* __restrict__ Uws, float* __restrict__ distP, float* __restrict__ biasp)
{
    __shared__ float2 U[2][16][33];   // per-wave slice

    int wv   = threadIdx.x >> 6;
    int l64  = threadIdx.x & 63;
    int rh   = l64 >> 5;
    int col  = l64 & 31;
    int sbase = rh << 5;

    int gp = blockIdx.x * 2 + wv;     // 4097*2 == 8194 == NPROB exactly
    int h, w; prob_to_hw(gp, h, w);
    int hc = (128 - h) & 127, wc = (128 - w) & 127;
    bool self = (hc == h && wc == w);

    v2f b[16];
    build_kcol_half(ker, h, w, col, rh, b);

    // tracked column norm^2 (identical across rh halves by construction)
    float cn;
    {
        float nr = 0.f;
        #pragma unroll
        for (int i = 0; i < 16; ++i) nr = fmaf(b[i].x, b[i].x, fmaf(b[i].y, b[i].y, nr));
        cn = nr + __shfl_xor(nr, 32, 64);
    }

    // ---- one-sided Jacobi: 31 XOR masks per sweep (DPP-able ones first) ----
    for (int sweep = 0; sweep < 6; ++sweep) {
        float offacc = 0.f;
        round_dpp<DPP_XOR1 >(b, cn, offacc, col, 1);
        round_dpp<DPP_XOR2 >(b, cn, offacc, col, 2);
        round_dpp<DPP_XOR3 >(b, cn, offacc, col, 3);
        round_dpp<DPP_XOR7 >(b, cn, offacc, col, 7);
        round_dpp<DPP_XOR15>(b, cn, offacc, col, 15);
        for (int m = 4; m < 32; ++m) {
            if (m == 7 || m == 15) continue;
            round_ds(b, cn, offacc, col, m);
        }
        // convergence: sum|g|^2 (pair-double-counted) <= 1e-5 * sum(sigma^4)
        float dg   = halfsum(cn * cn);
        float offT = halfsum(offacc);
        if (!__ballot(offT > 1e-5f * dg)) break;
    }

    // ---- top-16 selection by EXACT column norm; write normalized U ----
    float nr = 0.f;
    #pragma unroll
    for (int i = 0; i < 16; ++i) nr = fmaf(b[i].x, b[i].x, fmaf(b[i].y, b[i].y, nr));
    float nrF = nr + __shfl_xor(nr, 32, 64);
    int rank = 0;
    #pragma unroll
    for (int k = 0; k < 32; ++k) {
        float nk = __shfl(nrF, k, 64);
        if (nk > nrF || (nk == nrF && k < col)) ++rank;
    }
    bool sel = rank < 16;
    unsigned long long ball = __ballot(sel);
    unsigned cmask = (unsigned)(ball & 0xFFFFFFFFull);
    int rsel = __popc(cmask & ((1u << col) - 1u));
    float rin = rsqrtf(fmaxf(nrF, 1e-30f));
    if (sel) {
        #pragma unroll
        for (int j = 0; j < 16; ++j) {
            float2 uv = make_float2(b[j].x * rin, b[j].y * rin);
            U[wv][rsel][(rh << 4) + j] = uv;
            Uws[((size_t)gp * 16 + rsel) * 32 + (rh << 4) + j] = uv;
        }
    }
    asm volatile("s_waitcnt lgkmcnt(0)" ::: "memory");
    __builtin_amdgcn_sched_barrier(0);

    // ---- dist: ||K-P||^2 = ||K||^2 - 2 Re tr(K^H P) + 16 ----
    build_kcol_half(ker, h, w, col, rh, b);
    float kn = 0.f;
    #pragma unroll
    for (int j = 0; j < 16; ++j) kn = fmaf(b[j].x, b[j].x, fmaf(b[j].y, b[j].y, kn));
    float knt = wsum64(kn);
    float tr = 0.f;                            // both rh halves count -> 2x
    #pragma unroll
    for (int m = 0; m < 16; ++m) {
        float2 acc = make_float2(0.f, 0.f);
        #pragma unroll
        for (int j = 0; j < 16; ++j) {
            float2 um = U[wv][m][(rh << 4) + j];
            acc.x = fmaf(b[j].x, um.x, fmaf( b[j].y, um.y, acc.x));
            acc.y = fmaf(b[j].x, um.y, fmaf(-b[j].y, um.x, acc.y));
        }
        acc.x += __shfl_xor(acc.x, 32, 64);
        acc.y += __shfl_xor(acc.y, 32, 64);
        float2 w0 = U[wv][m][col];
        tr = fmaf(w0.x, acc.x, fmaf(w0.y, acc.y, tr));
    }
    float trt = wsum64(tr);                    // = 2 * Re tr(K^H P)
    if (l64 == 0) {
        float d2 = knt - trt + 16.f;
        distP[gp] = (self ? 1.f : 2.f) * d2;
    }

    // ---- bias correction at DC pixel (gp==8064 -> (h,w)=(0,0)) ----
    if (gp == 8064) {
        int mmode = col & 15;
        float2 d = make_float2(0.f, 0.f);
        #pragma unroll
        for (int j = 0; j < 16; ++j) {
            int i = (rh << 4) + j;
            float bv = bias[i];
            float2 ul = U[wv][mmode][i];
            d.x = fmaf(ul.x, bv, d.x);
            d.y = fmaf(-ul.y, bv, d.y);
        }
        d.x += __shfl_xor(d.x, 32, 64);
        d.y += __shfl_xor(d.y, 32, 64);
        float racc = 0.f;
        #pragma unroll
        for (int mm = 0; mm < 16; ++mm) {
            float dx = __shfl(d.x, sbase + mm, 64);
            float dy = __shfl(d.y, sbase + mm, 64);
            float2 ul = U[wv][mm][col];
            racc = fmaf(ul.x, dx, fmaf(-ul.y, dy, racc));
        }
        if (rh == 0) biasp[col] = bias[col] - racc;
    }
}

// Apply y_f = conj(P) x_f per pixel, rank-16 form. 8 consecutive pixels per
// block (one 64B line per (b,c) row -> coalesced). U staged in LDS.
__global__ __launch_bounds__(256) void k_apply(const float2* __restrict__ Uws,
                                               float2* __restrict__ XF)
{
    __shared__ float2 Us[16][33][9];   // [m][i][slot] (pads kill 8-way conflicts)
    __shared__ float2 xs[32][9];       // [c][slot]
    __shared__ float2 ts[16][9];       // [m][slot]

    int tid = threadIdx.x;
    int pb = blockIdx.x * 8;
    int h = pb >> 7, w0 = pb & 127;

    // --- stage U for the 8 pixels of this block ---
    {
        int slot = tid >> 5, t5 = tid & 31;
        int gp; bool cj;
        pix_to_prob(h, w0 + slot, gp, cj);
        size_t gbase = (size_t)gp * 512 + (size_t)t5 * 16;
        #pragma unroll
        for (int j = 0; j < 16; ++j) {
            int e = t5 * 16 + j;
            Us[e >> 5][e & 31][slot] = Uws[gbase + j];
        }
    }
    __syncthreads();

    int c = tid >> 3, ws = tid & 7;
    int gp; bool cj;
    pix_to_prob(h, w0 + ws, gp, cj);
    float sgn = cj ? -1.f : 1.f;
    long pbase = (long)h * 128 + (w0 + ws);

    for (int bb = 0; bb < NB; ++bb) {
        long adr = ((long)(bb * NCH + c)) * NPIX + pbase;
        xs[c][ws] = XF[adr];
        __syncthreads();
        if (c < 16) {
            float2 t = make_float2(0.f, 0.f);
            #pragma unroll
            for (int i = 0; i < 32; ++i) {
                float2 ul = Us[c][i][ws];
                float uy = sgn * ul.y;
                float2 xr = xs[i][ws];
                t.x = fmaf(ul.x, xr.x, fmaf(-uy, xr.y, t.x));
                t.y = fmaf(ul.x, xr.y, fmaf( uy, xr.x, t.y));
            }
            ts[c][ws] = t;
        }
        __syncthreads();
        float2 y = make_float2(0.f, 0.f);
        #pragma unroll
        for (int m = 0; m < 16; ++m) {
            float2 ul = Us[m][c][ws];
            float uy = sgn * ul.y;
            float2 t = ts[m][ws];
            y.x = fmaf(ul.x, t.x, fmaf( uy, t.y, y.x));
            y.y = fmaf(ul.x, t.y, fmaf(-uy, t.x, y.y));
        }
        XF[adr] = y;
        __syncthreads();
    }
}

__global__ __launch_bounds__(256) void k_inv_rows_bias(const float2* __restrict__ XF,
                                                       const float* __restrict__ biasp,
                                                       float* __restrict__ out) {
    __shared__ float2 buf[4][HW];
    int wave = threadIdx.x >> 6, lane = threadIdx.x & 63;
    long row = (long)blockIdx.x * 4 + wave;     // (b,o,h)
    int o = (int)((row >> 7) & 31);
    float bp = biasp[o];
    long base = row * HW;
    float2* d = buf[wave];
    d[lane]      = XF[base + lane];
    d[lane + 64] = XF[base + lane + 64];
    __syncthreads();
    fft128(d, lane, +1.f);
    const float sc = 1.0f / 128.0f;
    out[base + lane]      = d[lane].x * sc + bp;
    out[base + lane + 64] = d[lane + 64].x * sc + bp;
}

__global__ __launch_bounds__(256) void k_dist(const float* __restrict__ distP,
                                              float* __restrict__ out) {
    __shared__ float sh[256];
    float acc = 0.f;
    for (int i = threadIdx.x; i < NPROB; i += 256) acc += distP[i];
    sh[threadIdx.x] = acc;
    __syncthreads();
    for (int s = 128; s >= 1; s >>= 1) {
        if (threadIdx.x < s) sh[threadIdx.x] += sh[threadIdx.x + s];
        __syncthreads();
    }
    if (threadIdx.x == 0) out[(size_t)NB * NCH * NPIX] = sqrtf(sh[0]);
}

extern "C" void kernel_launch(void* const* d_in, const int* in_sizes, int n_in,
                              void* d_out, int out_size, void* d_ws, size_t ws_size,
                              hipStream_t stream) {
    (void)in_sizes; (void)n_in; (void)out_size; (void)ws_size;
    const float* x    = (const float*)d_in[0];
    const float* ker  = (const float*)d_in[1];
    const float* bias = (const float*)d_in[2];
    float* out = (float*)d_out;

    // ws: XF complex [16][32][128][128] (64 MiB) | distP [8194] | biasp [32]
    float2* XF   = (float2*)d_ws;
    float* distP = (float*)((char*)d_ws + (size_t)NB * NCH * NPIX * sizeof(float2));
    float* biasp = distP + NPROB;
    // U scratch in the tail of d_out (33.6 MB at +96 MB; overwritten later by
    // k_inv_rows_bias, which runs after k_apply has consumed it — stream order).
    float2* Uws = (float2*)((char*)d_out + ((size_t)96 << 20));

    int rows = NB * NCH * HW;   // 65536
    k_fwd_rows<<<dim3(rows / 4), dim3(256), 0, stream>>>(x, XF);
    k_cols<<<dim3(NB * NCH * 8), dim3(256), 0, stream>>>(XF, -1.f);
    k_eig6<<<dim3(NPROB / 2), dim3(128), 0, stream>>>(ker, bias, Uws, distP, biasp);
    k_apply<<<dim3(NPIX / 8), dim3(256), 0, stream>>>(Uws, XF);
    k_cols<<<dim3(NB * NCH * 8), dim3(256), 0, stream>>>(XF, +1.f);
    k_inv_rows_bias<<<dim3(rows / 4), dim3(256), 0, stream>>>(XF, biasp, out);
    k_dist<<<dim3(1), dim3(256), 0, stream>>>(distP, out);
}